// Round 1
// baseline (191591.223 us; speedup 1.0000x reference)
//
#include <hip/hip_runtime.h>
#include <math.h>

#define T_STEPS 65536
#define HID     512
#define NWG     64
#define WGSIZE  256

// Layout per workgroup (256 thr = 4 waves):
//   WG owns 8 h-indices: [wg*8, wg*8+8).
//   Wave wid owns 2 h-indices: wg*8 + wid*2 + {0,1}.
//   Within a wave: lane = r + 8*g, r in [0,8) = row-in-wave, g in [0,8) = k-group.
//     row r -> (jloc = r&1, gate = r>>1)  (gate order i,f,g,o as in PyTorch)
//     global gate row = gate*512 + wg*8 + wid*2 + jloc
//   Each lane holds 64 fp32 of W_hh and 64 of W_ih for its (row, k-slice).
//   k walk is staggered by group ((i+g)&15) so the 8 groups' ds_read_b128 hit
//   disjoint bank quads (conflict-free broadcast-ish reads of h/x from LDS).

__global__ __launch_bounds__(WGSIZE, 1)
void lstm_persistent(const float* __restrict__ x,      // [T,512]
                     const float* __restrict__ Wih,    // [2048,512]
                     const float* __restrict__ Whh,    // [2048,512]
                     const float* __restrict__ bih,    // [2048]
                     const float* __restrict__ bhh,    // [2048]
                     float* __restrict__ out,          // [512]
                     int*   flags,                     // [256], zeroed per launch
                     float* hbuf)                      // [2][512]
{
  const int wg   = blockIdx.x;
  const int tid  = threadIdx.x;
  const int wid  = tid >> 6;
  const int lane = tid & 63;
  const int r    = lane & 7;
  const int g    = lane >> 3;
  const int k0   = g << 6;            // 64-float k-slice start
  const int jloc = r & 1;
  const int gate = r >> 1;            // 0=i 1=f 2=g 3=o
  const int hidx = wg * 8 + wid * 2 + jloc;
  const int row  = gate * HID + hidx;

  __shared__ __align__(16) float hlds[512];
  __shared__ __align__(16) float xlds[512];

  // ---- load weights into registers (static indices only) ----
  float whh[64], wih[64];
#pragma unroll
  for (int i = 0; i < 16; ++i) {
    const int kk = k0 + (((i + g) & 15) << 2);
    float4 a = *reinterpret_cast<const float4*>(Whh + (size_t)row * 512 + kk);
    float4 b = *reinterpret_cast<const float4*>(Wih + (size_t)row * 512 + kk);
    whh[4*i+0] = a.x; whh[4*i+1] = a.y; whh[4*i+2] = a.z; whh[4*i+3] = a.w;
    wih[4*i+0] = b.x; wih[4*i+1] = b.y; wih[4*i+2] = b.z; wih[4*i+3] = b.w;
  }
  const float bias = bih[row] + bhh[row];

  // ---- stage x_0 ----
  if (tid < 128) {
    float4 v = reinterpret_cast<const float4*>(x)[tid];
    *reinterpret_cast<float4*>(xlds + tid * 4) = v;
  }
  __syncthreads();

  auto dot_lds = [&](const float* lds, const float* w) -> float {
    float acc = 0.f;
#pragma unroll
    for (int i = 0; i < 16; ++i) {
      const int kk = k0 + (((i + g) & 15) << 2);
      float4 v = *reinterpret_cast<const float4*>(lds + kk);
      acc = fmaf(w[4*i+0], v.x, acc);
      acc = fmaf(w[4*i+1], v.y, acc);
      acc = fmaf(w[4*i+2], v.z, acc);
      acc = fmaf(w[4*i+3], v.w, acc);
    }
    return acc;
  };

  float xacc = dot_lds(xlds, wih);   // x-projection partial for t=0
  float c    = 0.f;

#pragma unroll 1
  for (int t = 0; t < T_STEPS; ++t) {
    // ---- wait for all waves' h_{t-1} posts (wave 0 polls 256 flags) ----
    if (t > 0 && wid == 0) {
      const int* p = flags + lane * 4;
      while (true) {
        int a0 = __hip_atomic_load(p + 0, __ATOMIC_RELAXED, __HIP_MEMORY_SCOPE_AGENT);
        int a1 = __hip_atomic_load(p + 1, __ATOMIC_RELAXED, __HIP_MEMORY_SCOPE_AGENT);
        int a2 = __hip_atomic_load(p + 2, __ATOMIC_RELAXED, __HIP_MEMORY_SCOPE_AGENT);
        int a3 = __hip_atomic_load(p + 3, __ATOMIC_RELAXED, __HIP_MEMORY_SCOPE_AGENT);
        int m = min(min(a0, a1), min(a2, a3));
        if (__all(m >= t)) break;
        __builtin_amdgcn_s_sleep(1);
      }
    }
    __syncthreads();  // A: flags ready; also fences xlds/hlds reuse

    // ---- stage h_{t-1} (waves 0-1, LIC-coherent loads) and x_{t+1} (waves 2-3) ----
    if (t > 0 && tid < 128) {
      float* src = hbuf + (((t - 1) & 1) << 9) + (tid << 2);
      float v0 = __hip_atomic_load(src + 0, __ATOMIC_RELAXED, __HIP_MEMORY_SCOPE_AGENT);
      float v1 = __hip_atomic_load(src + 1, __ATOMIC_RELAXED, __HIP_MEMORY_SCOPE_AGENT);
      float v2 = __hip_atomic_load(src + 2, __ATOMIC_RELAXED, __HIP_MEMORY_SCOPE_AGENT);
      float v3 = __hip_atomic_load(src + 3, __ATOMIC_RELAXED, __HIP_MEMORY_SCOPE_AGENT);
      *reinterpret_cast<float4*>(hlds + (tid << 2)) = make_float4(v0, v1, v2, v3);
    }
    if (tid >= 128 && t + 1 < T_STEPS) {
      const int idx = tid - 128;
      float4 v = reinterpret_cast<const float4*>(x + (size_t)(t + 1) * 512)[idx];
      *reinterpret_cast<float4*>(xlds + idx * 4) = v;
    }
    __syncthreads();  // B

    // ---- gate pre-activation: xacc (precomputed) + h-dot, reduce over 8 k-groups ----
    float acc = xacc;
    if (t > 0) acc += dot_lds(hlds, whh);
    acc += __shfl_xor(acc, 8);
    acc += __shfl_xor(acc, 16);
    acc += __shfl_xor(acc, 32);
    acc += bias;

    // ---- nonlinearity: sigmoid for i,f,o; tanh (=2*sig(2x)-1) for g ----
    const bool isg = (gate == 2);
    float xs = isg ? 2.f * acc : acc;
    float s  = 1.f / (1.f + expf(-xs));
    float v  = isg ? (2.f * s - 1.f) : s;

    // ---- gather i,f,g,o for my jloc via in-wave shuffles ----
    float iv = __shfl(v, jloc + 0);
    float fv = __shfl(v, jloc + 2);
    float gv = __shfl(v, jloc + 4);
    float ov = __shfl(v, jloc + 6);

    c = fv * c + iv * gv;
    float e2 = expf(-2.f * c);
    float th = 2.f / (1.f + e2) - 1.f;
    float hn = ov * th;

    // ---- post h_t (lanes 0,1 of every wave), then per-wave flag ----
    if (lane < 2) {
      __hip_atomic_store(hbuf + ((t & 1) << 9) + wg * 8 + wid * 2 + lane, hn,
                         __ATOMIC_RELAXED, __HIP_MEMORY_SCOPE_AGENT);
    }
    asm volatile("s_waitcnt vmcnt(0)" ::: "memory");
    if (lane == 0) {
      __hip_atomic_store(flags + wg * 4 + wid, t + 1,
                         __ATOMIC_RELAXED, __HIP_MEMORY_SCOPE_AGENT);
    }

    // ---- overlap: x-projection partial for step t+1 (hides peers' latency) ----
    if (t + 1 < T_STEPS) xacc = dot_lds(xlds, wih);
  }

  // ---- softmax(h_{T-1}) by wg 0, wave 0 ----
  if (wg == 0) {
    if (wid == 0) {
      const int* p = flags + lane * 4;
      while (true) {
        int a0 = __hip_atomic_load(p + 0, __ATOMIC_RELAXED, __HIP_MEMORY_SCOPE_AGENT);
        int a1 = __hip_atomic_load(p + 1, __ATOMIC_RELAXED, __HIP_MEMORY_SCOPE_AGENT);
        int a2 = __hip_atomic_load(p + 2, __ATOMIC_RELAXED, __HIP_MEMORY_SCOPE_AGENT);
        int a3 = __hip_atomic_load(p + 3, __ATOMIC_RELAXED, __HIP_MEMORY_SCOPE_AGENT);
        int m = min(min(a0, a1), min(a2, a3));
        if (__all(m >= T_STEPS)) break;
        __builtin_amdgcn_s_sleep(1);
      }
      float* hsrc = hbuf + (((T_STEPS - 1) & 1) << 9);
      float hv[8];
#pragma unroll
      for (int m2 = 0; m2 < 8; ++m2)
        hv[m2] = __hip_atomic_load(hsrc + lane * 8 + m2,
                                   __ATOMIC_RELAXED, __HIP_MEMORY_SCOPE_AGENT);
      float mx = hv[0];
#pragma unroll
      for (int m2 = 1; m2 < 8; ++m2) mx = fmaxf(mx, hv[m2]);
      mx = fmaxf(mx, __shfl_xor(mx, 1));
      mx = fmaxf(mx, __shfl_xor(mx, 2));
      mx = fmaxf(mx, __shfl_xor(mx, 4));
      mx = fmaxf(mx, __shfl_xor(mx, 8));
      mx = fmaxf(mx, __shfl_xor(mx, 16));
      mx = fmaxf(mx, __shfl_xor(mx, 32));
      float ex[8], sum = 0.f;
#pragma unroll
      for (int m2 = 0; m2 < 8; ++m2) { ex[m2] = expf(hv[m2] - mx); sum += ex[m2]; }
      sum += __shfl_xor(sum, 1);
      sum += __shfl_xor(sum, 2);
      sum += __shfl_xor(sum, 4);
      sum += __shfl_xor(sum, 8);
      sum += __shfl_xor(sum, 16);
      sum += __shfl_xor(sum, 32);
      float inv = 1.f / sum;
#pragma unroll
      for (int m2 = 0; m2 < 8; ++m2) out[lane * 8 + m2] = ex[m2] * inv;
    }
  }
}

extern "C" void kernel_launch(void* const* d_in, const int* in_sizes, int n_in,
                              void* d_out, int out_size, void* d_ws, size_t ws_size,
                              hipStream_t stream) {
  const float* x   = (const float*)d_in[0];
  const float* Wih = (const float*)d_in[1];
  const float* Whh = (const float*)d_in[2];
  const float* bih = (const float*)d_in[3];
  const float* bhh = (const float*)d_in[4];
  float* out   = (float*)d_out;
  int*   flags = (int*)d_ws;                       // 256 ints (1 KB)
  float* hbuf  = (float*)((char*)d_ws + 1024);     // 2 x 512 floats (4 KB)

  hipMemsetAsync(d_ws, 0, 1024, stream);           // zero flags each launch (capture-safe)
  lstm_persistent<<<NWG, WGSIZE, 0, stream>>>(x, Wih, Whh, bih, bhh, out, flags, hbuf);
}

// Round 2
// 106500.073 us; speedup vs baseline: 1.7990x; 1.7990x over previous
//
#include <hip/hip_runtime.h>
#include <math.h>

#define T_STEPS 65536
#define HID     512
#define NWG     64
#define WGSIZE  256

// Layout per workgroup (256 thr = 4 waves):
//   WG owns 8 h-indices: [wg*8, wg*8+8).
//   Wave wid owns 2 h-indices: wg*8 + wid*2 + {0,1}.
//   Within a wave: lane = r + 8*g, r in [0,8) = row-in-wave, g in [0,8) = k-group.
//     row r -> (jloc = r&1, gate = r>>1)  (gate order i,f,g,o as in PyTorch)
//   Each lane holds 64 fp32 of W_hh and 64 of W_ih for its (row, k-slice).
//
// Cross-WG h exchange: hbuf[2][512] of packed 8B words (hi32 = tag = t+1,
// lo32 = f32 bits of h). One relaxed agent-scope 8B store per element —
// no separate flag, no producer-side vmcnt wait. Consumers poll the tagged
// words directly (256 threads x 2 words) and drop values into LDS on match.

__global__ __launch_bounds__(WGSIZE, 1)
void lstm_persistent(const float* __restrict__ x,      // [T,512]
                     const float* __restrict__ Wih,    // [2048,512]
                     const float* __restrict__ Whh,    // [2048,512]
                     const float* __restrict__ bih,    // [2048]
                     const float* __restrict__ bhh,    // [2048]
                     float* __restrict__ out,          // [512]
                     unsigned long long* hbuf)         // [2][512] tagged pairs
{
  const int wg   = blockIdx.x;
  const int tid  = threadIdx.x;
  const int wid  = tid >> 6;
  const int lane = tid & 63;
  const int r    = lane & 7;
  const int g    = lane >> 3;
  const int k0   = g << 6;            // 64-float k-slice start
  const int jloc = r & 1;
  const int gate = r >> 1;            // 0=i 1=f 2=g 3=o
  const int hidx = wg * 8 + wid * 2 + jloc;
  const int row  = gate * HID + hidx;

  __shared__ __align__(16) float hlds[512];
  __shared__ __align__(16) float xlds[512];

  // ---- load weights into registers (static indices only) ----
  float whh[64], wih[64];
#pragma unroll
  for (int i = 0; i < 16; ++i) {
    const int kk = k0 + (((i + g) & 15) << 2);
    float4 a = *reinterpret_cast<const float4*>(Whh + (size_t)row * 512 + kk);
    float4 b = *reinterpret_cast<const float4*>(Wih + (size_t)row * 512 + kk);
    whh[4*i+0] = a.x; whh[4*i+1] = a.y; whh[4*i+2] = a.z; whh[4*i+3] = a.w;
    wih[4*i+0] = b.x; wih[4*i+1] = b.y; wih[4*i+2] = b.z; wih[4*i+3] = b.w;
  }
  const float bias = bih[row] + bhh[row];

  // ---- stage x_0 ----
  if (tid < 128) {
    float4 v = reinterpret_cast<const float4*>(x)[tid];
    *reinterpret_cast<float4*>(xlds + tid * 4) = v;
  }
  __syncthreads();

  auto dot_lds = [&](const float* lds, const float* w) -> float {
    float acc = 0.f;
#pragma unroll
    for (int i = 0; i < 16; ++i) {
      const int kk = k0 + (((i + g) & 15) << 2);
      float4 v = *reinterpret_cast<const float4*>(lds + kk);
      acc = fmaf(w[4*i+0], v.x, acc);
      acc = fmaf(w[4*i+1], v.y, acc);
      acc = fmaf(w[4*i+2], v.z, acc);
      acc = fmaf(w[4*i+3], v.w, acc);
    }
    return acc;
  };

  float xacc = dot_lds(xlds, wih);   // x-projection partial for t=0
  float c    = 0.f;

#pragma unroll 1
  for (int t = 0; t < T_STEPS; ++t) {
    // ---- stage: poll tagged h_{t-1} (all threads, 2 words each) + x_{t+1} ----
    float4 xv;
    const bool do_x = (tid < 128) && (t + 1 < T_STEPS);
    if (do_x) xv = reinterpret_cast<const float4*>(x + (size_t)(t + 1) * 512)[tid];

    if (t > 0) {
      const unsigned long long* src = hbuf + (((t - 1) & 1) << 9) + (tid << 1);
      const unsigned exp = (unsigned)t;
      unsigned long long p0, p1;
      while (true) {
        p0 = __hip_atomic_load(src + 0, __ATOMIC_RELAXED, __HIP_MEMORY_SCOPE_AGENT);
        p1 = __hip_atomic_load(src + 1, __ATOMIC_RELAXED, __HIP_MEMORY_SCOPE_AGENT);
        if ((unsigned)(p0 >> 32) == exp && (unsigned)(p1 >> 32) == exp) break;
      }
      hlds[(tid << 1) + 0] = __uint_as_float((unsigned)p0);
      hlds[(tid << 1) + 1] = __uint_as_float((unsigned)p1);
    }
    if (do_x) *reinterpret_cast<float4*>(xlds + tid * 4) = xv;
    __syncthreads();  // staging complete

    // ---- gate pre-activation: xacc (precomputed) + h-dot, reduce over 8 k-groups ----
    float acc = xacc;
    if (t > 0) acc += dot_lds(hlds, whh);
    acc += __shfl_xor(acc, 8);
    acc += __shfl_xor(acc, 16);
    acc += __shfl_xor(acc, 32);
    acc += bias;

    // ---- nonlinearity: sigmoid for i,f,o; tanh (=2*sig(2x)-1) for g ----
    const bool isg = (gate == 2);
    float xs = isg ? 2.f * acc : acc;
    float s  = 1.f / (1.f + expf(-xs));
    float v  = isg ? (2.f * s - 1.f) : s;

    // ---- gather i,f,g,o for my jloc via in-wave shuffles ----
    float iv = __shfl(v, jloc + 0);
    float fv = __shfl(v, jloc + 2);
    float gv = __shfl(v, jloc + 4);
    float ov = __shfl(v, jloc + 6);

    c = fv * c + iv * gv;
    float e2 = expf(-2.f * c);
    float th = 2.f / (1.f + e2) - 1.f;
    float hn = ov * th;

    // ---- post tagged h_t (lanes 0,1 of every wave): single 8B fire-and-forget ----
    if (lane < 2) {
      unsigned long long pk =
          ((unsigned long long)(unsigned)(t + 1) << 32) | (unsigned)__float_as_uint(hn);
      __hip_atomic_store(hbuf + ((t & 1) << 9) + wg * 8 + wid * 2 + lane, pk,
                         __ATOMIC_RELAXED, __HIP_MEMORY_SCOPE_AGENT);
    }

    // ---- overlap: x-projection partial for step t+1 (hides peers' latency) ----
    if (t + 1 < T_STEPS) xacc = dot_lds(xlds, wih);
    __syncthreads();  // everyone done with hlds/xlds before next staging
  }

  // ---- softmax(h_{T-1}) by wg 0, wave 0 ----
  if (wg == 0 && wid == 0) {
    const unsigned long long* src = hbuf + (((T_STEPS - 1) & 1) << 9);
    float hv[8];
    {
      unsigned long long p[8];
      while (true) {
        bool ok = true;
#pragma unroll
        for (int m2 = 0; m2 < 8; ++m2) {
          p[m2] = __hip_atomic_load(src + lane * 8 + m2,
                                    __ATOMIC_RELAXED, __HIP_MEMORY_SCOPE_AGENT);
          ok &= ((unsigned)(p[m2] >> 32) == (unsigned)T_STEPS);
        }
        if (__all(ok)) break;
      }
#pragma unroll
      for (int m2 = 0; m2 < 8; ++m2) hv[m2] = __uint_as_float((unsigned)p[m2]);
    }
    float mx = hv[0];
#pragma unroll
    for (int m2 = 1; m2 < 8; ++m2) mx = fmaxf(mx, hv[m2]);
    mx = fmaxf(mx, __shfl_xor(mx, 1));
    mx = fmaxf(mx, __shfl_xor(mx, 2));
    mx = fmaxf(mx, __shfl_xor(mx, 4));
    mx = fmaxf(mx, __shfl_xor(mx, 8));
    mx = fmaxf(mx, __shfl_xor(mx, 16));
    mx = fmaxf(mx, __shfl_xor(mx, 32));
    float ex[8], sum = 0.f;
#pragma unroll
    for (int m2 = 0; m2 < 8; ++m2) { ex[m2] = expf(hv[m2] - mx); sum += ex[m2]; }
    sum += __shfl_xor(sum, 1);
    sum += __shfl_xor(sum, 2);
    sum += __shfl_xor(sum, 4);
    sum += __shfl_xor(sum, 8);
    sum += __shfl_xor(sum, 16);
    sum += __shfl_xor(sum, 32);
    float inv = 1.f / sum;
#pragma unroll
    for (int m2 = 0; m2 < 8; ++m2) out[lane * 8 + m2] = ex[m2] * inv;
  }
}

extern "C" void kernel_launch(void* const* d_in, const int* in_sizes, int n_in,
                              void* d_out, int out_size, void* d_ws, size_t ws_size,
                              hipStream_t stream) {
  const float* x   = (const float*)d_in[0];
  const float* Wih = (const float*)d_in[1];
  const float* Whh = (const float*)d_in[2];
  const float* bih = (const float*)d_in[3];
  const float* bhh = (const float*)d_in[4];
  float* out = (float*)d_out;
  unsigned long long* hbuf = (unsigned long long*)d_ws;  // 2 x 512 x 8B = 8 KB

  hipMemsetAsync(d_ws, 0, 8192, stream);  // zero tags each launch (capture-safe)
  lstm_persistent<<<NWG, WGSIZE, 0, stream>>>(x, Wih, Whh, bih, bhh, out, hbuf);
}